// Round 3
// baseline (1385.415 us; speedup 1.0000x reference)
//
#include <hip/hip_runtime.h>
#include <hip/hip_bf16.h>

#define T_TOK 8192
#define DMODEL 1024
#define DFF 2048
#define NEXP 8

typedef __attribute__((ext_vector_type(8))) short short8v;
typedef __attribute__((ext_vector_type(4))) float floatx4;
typedef __attribute__((ext_vector_type(4))) ushort ushort4v;

__device__ __forceinline__ ushort f2bf(float f) {
  union { float f; unsigned u; } v; v.f = f;
  unsigned u = v.u;
  unsigned r = (u + 0x7FFFu + ((u >> 16) & 1u)) >> 16;
  return (ushort)r;
}
__device__ __forceinline__ float bf2f(ushort b) {
  union { unsigned u; float f; } v; v.u = ((unsigned)b) << 16;
  return v.f;
}
__device__ __forceinline__ void gload16(const void* g, void* l) {
  __builtin_amdgcn_global_load_lds(
      (const __attribute__((address_space(1))) unsigned int*)g,
      (__attribute__((address_space(3))) unsigned int*)l, 16, 0, 0);
}

// ---------------- init: zero meta + entropy accumulator ----------------
__global__ void init_kernel(int* __restrict__ meta, float* __restrict__ entWs) {
  if (threadIdx.x < 64) meta[threadIdx.x] = 0;
  if (threadIdx.x == 0) *entWs = 0.f;
}

// ---------------- gating: logits, top-2, softmax, entropy; fused x->bf16 ----------------
// norm-modulation in the reference is a per-token uniform shift across experts:
// invariant for top-k indices and softmax(topv) -> skipped entirely.
__global__ __launch_bounds__(256) void gating_kernel(
    const float* __restrict__ x, const float* __restrict__ Wg,
    const float* __restrict__ bg, int* __restrict__ meta,
    int* __restrict__ te, float* __restrict__ tg, float* __restrict__ entWs,
    ushort* __restrict__ xb) {
  __shared__ float wgT[NEXP * DMODEL];
  __shared__ float sbg[NEXP];
  __shared__ float went[4];
  int tid = threadIdx.x;
  for (int idx = tid; idx < NEXP * DMODEL; idx += 256) {
    int d = idx >> 3, e = idx & 7;
    wgT[e * DMODEL + d] = Wg[idx];
  }
  if (tid < NEXP) sbg[tid] = bg[tid];
  __syncthreads();
  int wid = tid >> 6, lane = tid & 63;
  int t = blockIdx.x * 4 + wid;
  float acc[NEXP];
#pragma unroll
  for (int e = 0; e < NEXP; ++e) acc[e] = 0.f;
  const float* xr = x + (long)t * DMODEL;
  ushort* xbr = xb + (long)t * DMODEL;
#pragma unroll
  for (int i = 0; i < DMODEL / 64; ++i) {
    int d = lane + 64 * i;
    float xv = xr[d];
    xbr[d] = f2bf(xv);
#pragma unroll
    for (int e = 0; e < NEXP; ++e) acc[e] += xv * wgT[e * DMODEL + d];
  }
#pragma unroll
  for (int off = 32; off; off >>= 1)
#pragma unroll
    for (int e = 0; e < NEXP; ++e) acc[e] += __shfl_xor(acc[e], off, 64);
  if (lane == 0) {
    float lg[NEXP];
#pragma unroll
    for (int e = 0; e < NEXP; ++e) lg[e] = acc[e] + sbg[e];
    int e1 = 0; float v1 = lg[0];
#pragma unroll
    for (int e = 1; e < NEXP; ++e) if (lg[e] > v1) { v1 = lg[e]; e1 = e; }
    int e2 = -1; float v2 = -1e30f;
#pragma unroll
    for (int e = 0; e < NEXP; ++e) if (e != e1 && lg[e] > v2) { v2 = lg[e]; e2 = e; }
    float p2 = expf(v2 - v1);
    float s = 1.f + p2;
    float g1 = 1.f / s, g2 = p2 / s;
    float ent = -(g1 * logf(fmaxf(g1, 1e-8f)) + g2 * logf(fmaxf(g2, 1e-8f)));
    atomicAdd(&meta[e1], 1);
    atomicAdd(&meta[e2], 1);
    te[2 * t] = e1; te[2 * t + 1] = e2;
    tg[2 * t] = g1; tg[2 * t + 1] = g2;
    went[wid] = ent;
  }
  __syncthreads();
  if (tid == 0)
    atomicAdd(entWs, (went[0] + went[1] + went[2] + went[3]) * (1.f / T_TOK));
}

// meta layout (ints): counts @0..7, base @16..23, cursor @32..39
__global__ void prefix_kernel(int* __restrict__ meta) {
  if (threadIdx.x == 0) {
    int s = 0;
    for (int e = 0; e < NEXP; ++e) { meta[16 + e] = s; s += meta[e]; meta[32 + e] = 0; }
  }
}

__global__ void scatter_kernel(const int* __restrict__ te, const float* __restrict__ tg,
                               int* __restrict__ meta, int* __restrict__ tok,
                               float* __restrict__ gate, int* __restrict__ slotOf) {
  int t = blockIdx.x * blockDim.x + threadIdx.x;
  if (t >= T_TOK) return;
  for (int k = 0; k < 2; ++k) {
    int e = te[2 * t + k];
    int pos = atomicAdd(&meta[32 + e], 1);
    int slot = meta[16 + e] + pos;
    tok[slot] = t;
    gate[slot] = tg[2 * t + k];
    slotOf[2 * t + k] = slot;
  }
}

// ---------------- transpose + convert weights: src[e][R][C] f32 -> dst[e][C][R] bf16 ----------------
__global__ __launch_bounds__(256) void tcvt_kernel(const float* __restrict__ src,
                                                   ushort* __restrict__ dst,
                                                   int R, int C) {
  __shared__ ushort tile[64][72];
  int tid = threadIdx.x;
  long eoff = (long)blockIdx.z * R * C;
  int r0 = blockIdx.y * 64, c0 = blockIdx.x * 64;
  int lr = tid >> 4, lc = (tid & 15) * 4;
#pragma unroll
  for (int p = 0; p < 4; ++p) {
    int r = lr + p * 16;
    float4 v = *(const float4*)&src[eoff + (long)(r0 + r) * C + (c0 + lc)];
    tile[r][lc + 0] = f2bf(v.x); tile[r][lc + 1] = f2bf(v.y);
    tile[r][lc + 2] = f2bf(v.z); tile[r][lc + 3] = f2bf(v.w);
  }
  __syncthreads();
  int sr = tid >> 3, sc = (tid & 7) * 8;
#pragma unroll
  for (int p = 0; p < 2; ++p) {
    int c = sr + p * 32;
    short8v v;
#pragma unroll
    for (int j = 0; j < 8; ++j) v[j] = (short)tile[sc + j][c];
    *(short8v*)&dst[eoff + (long)(c0 + c) * R + (r0 + sc)] = v;
  }
}

// ================= grouped GEMMs: 256x256 tile, BK=64, double-buffered =================
// T3-minimum 2-phase dbuf: STAGE(next) issued before ds_read+MFMA(cur), one
// vmcnt(0)+barrier per K-tile (via __syncthreads drain semantics).

// ---------------- GEMM1: h = relu(x[tok] @ W1 + b1), bf16 out ----------------
__global__ __launch_bounds__(512) void gemm1_kernel(
    const ushort* __restrict__ xb, const ushort* __restrict__ w1t,
    const float* __restrict__ b1, const int* __restrict__ meta,
    const int* __restrict__ tok, ushort* __restrict__ h) {
  int e = blockIdx.z;
  int cnt = meta[e];
  int m0 = blockIdx.x * 256;
  if (m0 >= cnt) return;
  int n0 = blockIdx.y * 256;
  int bas = meta[16 + e];
  __shared__ ushort As[2][256 * 64];
  __shared__ ushort Bs[2][256 * 64];
  int tid = threadIdx.x;

  const ushort* w1e = w1t + (long)e * DFF * DMODEL + (long)n0 * DMODEL;
  const ushort* aS[4];
  const ushort* bS[4];
#pragma unroll
  for (int i = 0; i < 4; ++i) {
    int q = tid + 512 * i;
    int row = q >> 3, c8 = q & 7;
    int m = m0 + row; if (m >= cnt) m = cnt - 1;
    int tk = tok[bas + m];
    aS[i] = xb + (long)tk * DMODEL + c8 * 8;
    bS[i] = w1e + (long)row * DMODEL + c8 * 8;
  }

  floatx4 acc[8][4];
#pragma unroll
  for (int i = 0; i < 8; ++i)
#pragma unroll
    for (int j = 0; j < 4; ++j) acc[i][j] = (floatx4){0.f, 0.f, 0.f, 0.f};

  int wid = tid >> 6, lane = tid & 63;
  int wm = (wid >> 2) * 128, wn = (wid & 3) * 64;
  int lr = lane & 15, lg = lane >> 4;

  auto STAGE = [&](int buf, int k0) {
#pragma unroll
    for (int i = 0; i < 4; ++i) {
      int q = tid + 512 * i;
      gload16(aS[i] + k0, (char*)As[buf] + q * 16);
      gload16(bS[i] + k0, (char*)Bs[buf] + q * 16);
    }
  };
  auto COMPUTE = [&](int buf) {
#pragma unroll
    for (int ks = 0; ks < 2; ++ks) {
      short8v af[8], bfv[4];
#pragma unroll
      for (int mi = 0; mi < 8; ++mi)
        af[mi] = *(const short8v*)((const char*)As[buf] + ((wm + mi * 16 + lr) * 128 + ks * 64 + lg * 16));
#pragma unroll
      for (int ni = 0; ni < 4; ++ni)
        bfv[ni] = *(const short8v*)((const char*)Bs[buf] + ((wn + ni * 16 + lr) * 128 + ks * 64 + lg * 16));
#pragma unroll
      for (int mi = 0; mi < 8; ++mi)
#pragma unroll
        for (int ni = 0; ni < 4; ++ni)
          acc[mi][ni] = __builtin_amdgcn_mfma_f32_16x16x32_bf16(af[mi], bfv[ni], acc[mi][ni], 0, 0, 0);
    }
  };

  STAGE(0, 0);
  __syncthreads();
  for (int k0 = 0; k0 < DMODEL; k0 += 128) {
    if (k0 + 64 < DMODEL) STAGE(1, k0 + 64);
    COMPUTE(0);
    __syncthreads();
    if (k0 + 128 < DMODEL) STAGE(0, k0 + 128);
    COMPUTE(1);
    __syncthreads();
  }

  const float* b1e = b1 + e * DFF;
#pragma unroll
  for (int mi = 0; mi < 8; ++mi) {
#pragma unroll
    for (int r = 0; r < 4; ++r) {
      int m = m0 + wm + mi * 16 + lg * 4 + r;
      if (m >= cnt) continue;
      long hrow = (long)(bas + m) * DFF;
#pragma unroll
      for (int ni = 0; ni < 4; ++ni) {
        int f = n0 + wn + ni * 16 + lr;
        float v = acc[mi][ni][r] + b1e[f];
        h[hrow + f] = f2bf(fmaxf(v, 0.f));
      }
    }
  }
}

// ---------------- GEMM2: y[slot] = gate * (h[slot] @ W2 + b2), bf16, NO atomics ----------------
__global__ __launch_bounds__(512) void gemm2_kernel(
    const ushort* __restrict__ h, const ushort* __restrict__ w2t,
    const float* __restrict__ b2, const int* __restrict__ meta,
    const float* __restrict__ gate, ushort* __restrict__ y) {
  int e = blockIdx.z;
  int cnt = meta[e];
  int m0 = blockIdx.x * 256;
  if (m0 >= cnt) return;
  int n0 = blockIdx.y * 256;
  int bas = meta[16 + e];
  __shared__ ushort As[2][256 * 64];
  __shared__ ushort Bs[2][256 * 64];
  int tid = threadIdx.x;

  const ushort* w2e = w2t + (long)e * DMODEL * DFF + (long)n0 * DFF;
  const ushort* aS[4];
  const ushort* bS[4];
#pragma unroll
  for (int i = 0; i < 4; ++i) {
    int q = tid + 512 * i;
    int row = q >> 3, c8 = q & 7;
    int m = m0 + row; if (m >= cnt) m = cnt - 1;
    aS[i] = h + (long)(bas + m) * DFF + c8 * 8;
    bS[i] = w2e + (long)row * DFF + c8 * 8;
  }

  floatx4 acc[8][4];
#pragma unroll
  for (int i = 0; i < 8; ++i)
#pragma unroll
    for (int j = 0; j < 4; ++j) acc[i][j] = (floatx4){0.f, 0.f, 0.f, 0.f};

  int wid = tid >> 6, lane = tid & 63;
  int wm = (wid >> 2) * 128, wn = (wid & 3) * 64;
  int lr = lane & 15, lg = lane >> 4;

  auto STAGE = [&](int buf, int k0) {
#pragma unroll
    for (int i = 0; i < 4; ++i) {
      int q = tid + 512 * i;
      gload16(aS[i] + k0, (char*)As[buf] + q * 16);
      gload16(bS[i] + k0, (char*)Bs[buf] + q * 16);
    }
  };
  auto COMPUTE = [&](int buf) {
#pragma unroll
    for (int ks = 0; ks < 2; ++ks) {
      short8v af[8], bfv[4];
#pragma unroll
      for (int mi = 0; mi < 8; ++mi)
        af[mi] = *(const short8v*)((const char*)As[buf] + ((wm + mi * 16 + lr) * 128 + ks * 64 + lg * 16));
#pragma unroll
      for (int ni = 0; ni < 4; ++ni)
        bfv[ni] = *(const short8v*)((const char*)Bs[buf] + ((wn + ni * 16 + lr) * 128 + ks * 64 + lg * 16));
#pragma unroll
      for (int mi = 0; mi < 8; ++mi)
#pragma unroll
        for (int ni = 0; ni < 4; ++ni)
          acc[mi][ni] = __builtin_amdgcn_mfma_f32_16x16x32_bf16(af[mi], bfv[ni], acc[mi][ni], 0, 0, 0);
    }
  };

  STAGE(0, 0);
  __syncthreads();
  for (int k0 = 0; k0 < DFF; k0 += 128) {
    if (k0 + 64 < DFF) STAGE(1, k0 + 64);
    COMPUTE(0);
    __syncthreads();
    if (k0 + 128 < DFF) STAGE(0, k0 + 128);
    COMPUTE(1);
    __syncthreads();
  }

  const float* b2e = b2 + e * DMODEL;
#pragma unroll
  for (int mi = 0; mi < 8; ++mi) {
#pragma unroll
    for (int r = 0; r < 4; ++r) {
      int m = m0 + wm + mi * 16 + lg * 4 + r;
      if (m >= cnt) continue;
      int slot = bas + m;
      float g = gate[slot];
      ushort* yr = y + (long)slot * DMODEL;
#pragma unroll
      for (int ni = 0; ni < 4; ++ni) {
        int n = n0 + wn + ni * 16 + lr;
        float v = g * (acc[mi][ni][r] + b2e[n]);
        yr[n] = f2bf(v);
      }
    }
  }
}

// ---------------- combine: out[t] = y[slot1] + y[slot2]; entropy copy ----------------
__global__ __launch_bounds__(256) void combine_kernel(
    const ushort* __restrict__ y, const int* __restrict__ slotOf,
    const float* __restrict__ entWs, float* __restrict__ out) {
  int t = blockIdx.x;
  int s1 = slotOf[2 * t], s2 = slotOf[2 * t + 1];
  int d = threadIdx.x * 4;
  ushort4v a = *(const ushort4v*)&y[(long)s1 * DMODEL + d];
  ushort4v b = *(const ushort4v*)&y[(long)s2 * DMODEL + d];
  float4 r;
  r.x = bf2f(a[0]) + bf2f(b[0]);
  r.y = bf2f(a[1]) + bf2f(b[1]);
  r.z = bf2f(a[2]) + bf2f(b[2]);
  r.w = bf2f(a[3]) + bf2f(b[3]);
  *(float4*)&out[(long)t * DMODEL + d] = r;
  if (t == 0 && threadIdx.x == 0) out[(long)T_TOK * DMODEL] = *entWs;
}

extern "C" void kernel_launch(void* const* d_in, const int* in_sizes, int n_in,
                              void* d_out, int out_size, void* d_ws, size_t ws_size,
                              hipStream_t stream) {
  const float* x  = (const float*)d_in[0];
  const float* Wg = (const float*)d_in[1];
  const float* bg = (const float*)d_in[2];
  const float* W1 = (const float*)d_in[3];
  const float* b1 = (const float*)d_in[4];
  const float* W2 = (const float*)d_in[5];
  const float* b2 = (const float*)d_in[6];
  float* out = (float*)d_out;

  char* ws = (char*)d_ws;
  int*    meta   = (int*)(ws + 0);            // 256B (counts/base/cursor)
  float*  entWs  = (float*)(ws + 256);
  int*    te     = (int*)(ws + 1024);         // 64 KB
  float*  tg     = (float*)(ws + 66560);      // 64 KB
  int*    tokA   = (int*)(ws + 132096);       // 64 KB
  float*  gate   = (float*)(ws + 197632);     // 64 KB
  int*    slotOf = (int*)(ws + 263168);       // 64 KB
  ushort* xb     = (ushort*)(ws + 328704);    // 16 MB
  ushort* w1t    = (ushort*)(ws + 17105920);  // 32 MB  (dead after gemm1 -> reused as y)
  ushort* w2t    = (ushort*)(ws + 50660352);  // 32 MB
  ushort* h      = (ushort*)(ws + 84214784);  // 64 MB  (total ~151.3 MB)
  ushort* y      = w1t;                       // alias: w1t consumed by gemm1 before gemm2 writes y

  init_kernel<<<1, 64, 0, stream>>>(meta, entWs);
  gating_kernel<<<T_TOK / 4, 256, 0, stream>>>(x, Wg, bg, meta, te, tg, entWs, xb);
  prefix_kernel<<<1, 1, 0, stream>>>(meta);
  scatter_kernel<<<T_TOK / 256, 256, 0, stream>>>(te, tg, meta, tokA, gate, slotOf);
  tcvt_kernel<<<dim3(DFF / 64, DMODEL / 64, NEXP), 256, 0, stream>>>(W1, w1t, DMODEL, DFF);
  tcvt_kernel<<<dim3(DMODEL / 64, DFF / 64, NEXP), 256, 0, stream>>>(W2, w2t, DFF, DMODEL);
  gemm1_kernel<<<dim3(32, DFF / 256, NEXP), 512, 0, stream>>>(xb, w1t, b1, meta, tokA, h);
  gemm2_kernel<<<dim3(32, DMODEL / 256, NEXP), 512, 0, stream>>>(h, w2t, b2, meta, gate, y);
  combine_kernel<<<T_TOK, 256, 0, stream>>>(y, slotOf, entWs, out);
}

// Round 4
// 526.112 us; speedup vs baseline: 2.6333x; 2.6333x over previous
//
#include <hip/hip_runtime.h>
#include <hip/hip_bf16.h>

#define T_TOK 8192
#define DMODEL 1024
#define DFF 2048
#define NEXP 8

typedef __attribute__((ext_vector_type(8))) short short8v;
typedef __attribute__((ext_vector_type(4))) float floatx4;
typedef __attribute__((ext_vector_type(4))) ushort ushort4v;

__device__ __forceinline__ ushort f2bf(float f) {
  union { float f; unsigned u; } v; v.f = f;
  unsigned u = v.u;
  unsigned r = (u + 0x7FFFu + ((u >> 16) & 1u)) >> 16;
  return (ushort)r;
}
__device__ __forceinline__ float bf2f(ushort b) {
  union { unsigned u; float f; } v; v.u = ((unsigned)b) << 16;
  return v.f;
}
__device__ __forceinline__ void gload16(const void* g, void* l) {
  __builtin_amdgcn_global_load_lds(
      (const __attribute__((address_space(1))) unsigned int*)g,
      (__attribute__((address_space(3))) unsigned int*)l, 16, 0, 0);
}
__device__ __forceinline__ short8v dsr128(unsigned off) {
  short8v r;
  asm volatile("ds_read_b128 %0, %1" : "=v"(r) : "v"(off));
  return r;
}
#define VMW(n) asm volatile("s_waitcnt vmcnt(" #n ")" ::: "memory")
#define LG0()  asm volatile("s_waitcnt lgkmcnt(0)" ::: "memory")
#define BAR()  asm volatile("s_barrier" ::: "memory")
#define SB0()  __builtin_amdgcn_sched_barrier(0)

// ---------------- init ----------------
__global__ void init_kernel(int* __restrict__ meta, float* __restrict__ entWs) {
  if (threadIdx.x < 64) meta[threadIdx.x] = 0;
  if (threadIdx.x == 0) *entWs = 0.f;
}

// ---------------- gating (norm-modulation is a uniform per-token shift: skipped) ----------------
__global__ __launch_bounds__(256) void gating_kernel(
    const float* __restrict__ x, const float* __restrict__ Wg,
    const float* __restrict__ bg, int* __restrict__ meta,
    int* __restrict__ te, float* __restrict__ tg, float* __restrict__ entWs,
    ushort* __restrict__ xb) {
  __shared__ float wgT[NEXP * DMODEL];
  __shared__ float sbg[NEXP];
  __shared__ float went[4];
  int tid = threadIdx.x;
  for (int idx = tid; idx < NEXP * DMODEL; idx += 256) {
    int d = idx >> 3, e = idx & 7;
    wgT[e * DMODEL + d] = Wg[idx];
  }
  if (tid < NEXP) sbg[tid] = bg[tid];
  __syncthreads();
  int wid = tid >> 6, lane = tid & 63;
  int t = blockIdx.x * 4 + wid;
  float acc[NEXP];
#pragma unroll
  for (int e = 0; e < NEXP; ++e) acc[e] = 0.f;
  const float* xr = x + (long)t * DMODEL;
  ushort* xbr = xb + (long)t * DMODEL;
#pragma unroll
  for (int i = 0; i < DMODEL / 64; ++i) {
    int d = lane + 64 * i;
    float xv = xr[d];
    xbr[d] = f2bf(xv);
#pragma unroll
    for (int e = 0; e < NEXP; ++e) acc[e] += xv * wgT[e * DMODEL + d];
  }
#pragma unroll
  for (int off = 32; off; off >>= 1)
#pragma unroll
    for (int e = 0; e < NEXP; ++e) acc[e] += __shfl_xor(acc[e], off, 64);
  if (lane == 0) {
    float lg[NEXP];
#pragma unroll
    for (int e = 0; e < NEXP; ++e) lg[e] = acc[e] + sbg[e];
    int e1 = 0; float v1 = lg[0];
#pragma unroll
    for (int e = 1; e < NEXP; ++e) if (lg[e] > v1) { v1 = lg[e]; e1 = e; }
    int e2 = -1; float v2 = -1e30f;
#pragma unroll
    for (int e = 0; e < NEXP; ++e) if (e != e1 && lg[e] > v2) { v2 = lg[e]; e2 = e; }
    float p2 = expf(v2 - v1);
    float s = 1.f + p2;
    float g1 = 1.f / s, g2 = p2 / s;
    float ent = -(g1 * logf(fmaxf(g1, 1e-8f)) + g2 * logf(fmaxf(g2, 1e-8f)));
    atomicAdd(&meta[e1], 1);
    atomicAdd(&meta[e2], 1);
    te[2 * t] = e1; te[2 * t + 1] = e2;
    tg[2 * t] = g1; tg[2 * t + 1] = g2;
    went[wid] = ent;
  }
  __syncthreads();
  if (tid == 0)
    atomicAdd(entWs, (went[0] + went[1] + went[2] + went[3]) * (1.f / T_TOK));
}

// meta layout (ints): counts @0..7, base @16..23, cursor @32..39
__global__ void prefix_kernel(int* __restrict__ meta) {
  if (threadIdx.x == 0) {
    int s = 0;
    for (int e = 0; e < NEXP; ++e) { meta[16 + e] = s; s += meta[e]; meta[32 + e] = 0; }
  }
}

__global__ void scatter_kernel(const int* __restrict__ te, const float* __restrict__ tg,
                               int* __restrict__ meta, int* __restrict__ tok,
                               float* __restrict__ gate, int* __restrict__ slotOf) {
  int t = blockIdx.x * blockDim.x + threadIdx.x;
  if (t >= T_TOK) return;
  for (int k = 0; k < 2; ++k) {
    int e = te[2 * t + k];
    int pos = atomicAdd(&meta[32 + e], 1);
    int slot = meta[16 + e] + pos;
    tok[slot] = t;
    gate[slot] = tg[2 * t + k];
    slotOf[2 * t + k] = slot;
  }
}

// ---------------- transpose + convert weights: src[e][R][C] f32 -> dst[e][C][R] bf16 ----------------
__global__ __launch_bounds__(256) void tcvt_kernel(const float* __restrict__ src,
                                                   ushort* __restrict__ dst,
                                                   int R, int C) {
  __shared__ ushort tile[64][72];
  int tid = threadIdx.x;
  long eoff = (long)blockIdx.z * R * C;
  int r0 = blockIdx.y * 64, c0 = blockIdx.x * 64;
  int lr = tid >> 4, lc = (tid & 15) * 4;
#pragma unroll
  for (int p = 0; p < 4; ++p) {
    int r = lr + p * 16;
    float4 v = *(const float4*)&src[eoff + (long)(r0 + r) * C + (c0 + lc)];
    tile[r][lc + 0] = f2bf(v.x); tile[r][lc + 1] = f2bf(v.y);
    tile[r][lc + 2] = f2bf(v.z); tile[r][lc + 3] = f2bf(v.w);
  }
  __syncthreads();
  int sr = tid >> 3, sc = (tid & 7) * 8;
#pragma unroll
  for (int p = 0; p < 2; ++p) {
    int c = sr + p * 32;
    short8v v;
#pragma unroll
    for (int j = 0; j < 8; ++j) v[j] = (short)tile[sc + j][c];
    *(short8v*)&dst[eoff + (long)(c0 + c) * R + (r0 + sc)] = v;
  }
}

// ================= 8-phase pipelined grouped GEMM core =================
// 256x256 tile, BK=64 split into two ks-halves; LDS [buf][ks][256][32] bf16,
// XOR-swizzle ((row>>1)&3)<<4 within the 64B half (2-way conflicts = free).
// Counted vmcnt: 8 in steady state (4 half-tiles in flight), 4/0 in tail.
__device__ __forceinline__ void gemm_pipe(
    int NT, const char* aP0, const char* aP1, const char* bP0, const char* bP1,
    char* lds, int tid, floatx4 (&acc)[8][4]) {
  const unsigned ldsU = (unsigned)(unsigned long)lds;
  int lane = tid & 63, wid = tid >> 6;
  int wm = (wid >> 2) * 128, wn = (wid & 3) * 64;
  int lr = lane & 15, lg = lane >> 4;
  unsigned offA[8], offB[4];
#pragma unroll
  for (int mi = 0; mi < 8; ++mi) {
    int row = wm + mi * 16 + lr;
    offA[mi] = row * 64 + ((lg * 16) ^ (((row >> 1) & 3) << 4));
  }
#pragma unroll
  for (int ni = 0; ni < 4; ++ni) {
    int row = wn + ni * 16 + lr;
    offB[ni] = row * 64 + ((lg * 16) ^ (((row >> 1) & 3) << 4));
  }
  int r0 = tid >> 2, r1 = r0 + 128;
  unsigned scol0 = ((tid & 3) * 16) ^ (((r0 >> 1) & 3) << 4);
  unsigned scol1 = ((tid & 3) * 16) ^ (((r1 >> 1) & 3) << 4);

  auto STG_A = [&](int buf, int ks, int t) {
    int koff = t * 128 + ks * 64;
    int reg = (buf * 2 + ks) * 16384;
    gload16(aP0 + koff + scol0, lds + reg + tid * 16);
    gload16(aP1 + koff + scol1, lds + reg + 8192 + tid * 16);
  };
  auto STG_B = [&](int buf, int ks, int t) {
    int koff = t * 128 + ks * 64;
    int reg = 65536 + (buf * 2 + ks) * 16384;
    gload16(bP0 + koff + scol0, lds + reg + tid * 16);
    gload16(bP1 + koff + scol1, lds + reg + 8192 + tid * 16);
  };
  auto RDA = [&](int buf, int ks, int mi) {
    return dsr128(ldsU + (unsigned)((buf * 2 + ks) * 16384) + offA[mi]);
  };
  auto RDB = [&](int buf, int ks, int ni) {
    return dsr128(ldsU + (unsigned)(65536 + (buf * 2 + ks) * 16384) + offB[ni]);
  };
  auto MM = [&](int mh, short8v* af, short8v* bf) {
#pragma unroll
    for (int mi = 0; mi < 4; ++mi)
#pragma unroll
      for (int ni = 0; ni < 4; ++ni)
        acc[mh * 4 + mi][ni] =
            __builtin_amdgcn_mfma_f32_16x16x32_bf16(af[mi], bf[ni], acc[mh * 4 + mi][ni], 0, 0, 0);
  };

  // prologue: t0 all 4 half-tiles, t1 ks0 halves (12 loads); wait first 4.
  STG_A(0, 0, 0); STG_B(0, 0, 0);
  STG_A(0, 1, 0); STG_B(0, 1, 0);
  STG_A(1, 0, 1); STG_B(1, 0, 1);
  VMW(8); BAR();

  short8v af[4], bf0[4], bf1[4];
  for (int t = 0; t + 2 < NT; ++t) {
    int buf = t & 1, nb = buf ^ 1;
    // ph0: (ks0, mh0) ; stage (t+1).A.ks1
#pragma unroll
    for (int ni = 0; ni < 4; ++ni) bf0[ni] = RDB(buf, 0, ni);
#pragma unroll
    for (int i = 0; i < 4; ++i) af[i] = RDA(buf, 0, i);
    STG_A(nb, 1, t + 1);
    BAR(); LG0(); SB0();
    __builtin_amdgcn_s_setprio(1); MM(0, af, bf0); __builtin_amdgcn_s_setprio(0);
    SB0(); BAR();
    // ph1: (ks0, mh1) ; stage (t+1).B.ks1 ; vmcnt(8)
#pragma unroll
    for (int i = 0; i < 4; ++i) af[i] = RDA(buf, 0, 4 + i);
    STG_B(nb, 1, t + 1);
    VMW(8);
    BAR(); LG0(); SB0();
    __builtin_amdgcn_s_setprio(1); MM(1, af, bf0); __builtin_amdgcn_s_setprio(0);
    SB0(); BAR();
    // ph2: (ks1, mh0) ; stage (t+2).A.ks0
#pragma unroll
    for (int ni = 0; ni < 4; ++ni) bf1[ni] = RDB(buf, 1, ni);
#pragma unroll
    for (int i = 0; i < 4; ++i) af[i] = RDA(buf, 1, i);
    STG_A(buf, 0, t + 2);
    BAR(); LG0(); SB0();
    __builtin_amdgcn_s_setprio(1); MM(0, af, bf1); __builtin_amdgcn_s_setprio(0);
    SB0(); BAR();
    // ph3: (ks1, mh1) ; stage (t+2).B.ks0 ; vmcnt(8)
#pragma unroll
    for (int i = 0; i < 4; ++i) af[i] = RDA(buf, 1, 4 + i);
    STG_B(buf, 0, t + 2);
    VMW(8);
    BAR(); LG0(); SB0();
    __builtin_amdgcn_s_setprio(1); MM(1, af, bf1); __builtin_amdgcn_s_setprio(0);
    SB0(); BAR();
  }
  { // tile NT-2: stage only (NT-1).ks1 halves; waits 8 then 4
    int t = NT - 2, buf = t & 1, nb = buf ^ 1;
#pragma unroll
    for (int ni = 0; ni < 4; ++ni) bf0[ni] = RDB(buf, 0, ni);
#pragma unroll
    for (int i = 0; i < 4; ++i) af[i] = RDA(buf, 0, i);
    STG_A(nb, 1, t + 1);
    BAR(); LG0(); SB0();
    __builtin_amdgcn_s_setprio(1); MM(0, af, bf0); __builtin_amdgcn_s_setprio(0);
    SB0(); BAR();
#pragma unroll
    for (int i = 0; i < 4; ++i) af[i] = RDA(buf, 0, 4 + i);
    STG_B(nb, 1, t + 1);
    VMW(8);
    BAR(); LG0(); SB0();
    __builtin_amdgcn_s_setprio(1); MM(1, af, bf0); __builtin_amdgcn_s_setprio(0);
    SB0(); BAR();
#pragma unroll
    for (int ni = 0; ni < 4; ++ni) bf1[ni] = RDB(buf, 1, ni);
#pragma unroll
    for (int i = 0; i < 4; ++i) af[i] = RDA(buf, 1, i);
    BAR(); LG0(); SB0();
    __builtin_amdgcn_s_setprio(1); MM(0, af, bf1); __builtin_amdgcn_s_setprio(0);
    SB0(); BAR();
#pragma unroll
    for (int i = 0; i < 4; ++i) af[i] = RDA(buf, 1, 4 + i);
    VMW(4);
    BAR(); LG0(); SB0();
    __builtin_amdgcn_s_setprio(1); MM(1, af, bf1); __builtin_amdgcn_s_setprio(0);
    SB0(); BAR();
  }
  { // tile NT-1: no stages; vmcnt(0) before ks1 reads
    int t = NT - 1, buf = t & 1;
#pragma unroll
    for (int ni = 0; ni < 4; ++ni) bf0[ni] = RDB(buf, 0, ni);
#pragma unroll
    for (int i = 0; i < 4; ++i) af[i] = RDA(buf, 0, i);
    BAR(); LG0(); SB0();
    __builtin_amdgcn_s_setprio(1); MM(0, af, bf0); __builtin_amdgcn_s_setprio(0);
    SB0(); BAR();
#pragma unroll
    for (int i = 0; i < 4; ++i) af[i] = RDA(buf, 0, 4 + i);
    VMW(0);
    BAR(); LG0(); SB0();
    __builtin_amdgcn_s_setprio(1); MM(1, af, bf0); __builtin_amdgcn_s_setprio(0);
    SB0(); BAR();
#pragma unroll
    for (int ni = 0; ni < 4; ++ni) bf1[ni] = RDB(buf, 1, ni);
#pragma unroll
    for (int i = 0; i < 4; ++i) af[i] = RDA(buf, 1, i);
    BAR(); LG0(); SB0();
    __builtin_amdgcn_s_setprio(1); MM(0, af, bf1); __builtin_amdgcn_s_setprio(0);
    SB0(); BAR();
#pragma unroll
    for (int i = 0; i < 4; ++i) af[i] = RDA(buf, 1, 4 + i);
    BAR(); LG0(); SB0();
    __builtin_amdgcn_s_setprio(1); MM(1, af, bf1); __builtin_amdgcn_s_setprio(0);
    SB0(); BAR();
  }
}

// ---------------- GEMM1: h = relu(x[tok] @ W1 + b1) ----------------
__global__ __launch_bounds__(512) void gemm1_kernel(
    const ushort* __restrict__ xb, const ushort* __restrict__ w1t,
    const float* __restrict__ b1, const int* __restrict__ meta,
    const int* __restrict__ tok, ushort* __restrict__ h) {
  // bijective XCD swizzle (m204); wgid order: m fastest, then n, then e
  int nwg = 32 * (DFF / 256) * NEXP;
  int flat = blockIdx.x;
  int wgid = (flat % 8) * (nwg / 8) + flat / 8;
  int m0 = (wgid % 32) * 256;
  int rest = wgid / 32;
  int n0 = (rest % (DFF / 256)) * 256;
  int e = rest / (DFF / 256);
  int cnt = meta[e];
  if (m0 >= cnt) return;
  int bas = meta[16 + e];
  __shared__ char lds[131072];
  int tid = threadIdx.x;

  const char* w1e = (const char*)(w1t + (long)e * DFF * DMODEL + (long)n0 * DMODEL);
  int r0 = tid >> 2;
  int ma = m0 + r0; if (ma >= cnt) ma = cnt - 1;
  int mb = m0 + r0 + 128; if (mb >= cnt) mb = cnt - 1;
  const char* aP0 = (const char*)xb + (long)tok[bas + ma] * (DMODEL * 2);
  const char* aP1 = (const char*)xb + (long)tok[bas + mb] * (DMODEL * 2);
  const char* bP0 = w1e + (long)r0 * (DMODEL * 2);
  const char* bP1 = w1e + (long)(r0 + 128) * (DMODEL * 2);

  floatx4 acc[8][4];
#pragma unroll
  for (int i = 0; i < 8; ++i)
#pragma unroll
    for (int j = 0; j < 4; ++j) acc[i][j] = (floatx4){0.f, 0.f, 0.f, 0.f};

  gemm_pipe(DMODEL / 64, aP0, aP1, bP0, bP1, lds, tid, acc);

  int lane = tid & 63, wid = tid >> 6;
  int wm = (wid >> 2) * 128, wn = (wid & 3) * 64;
  int lr = lane & 15, lg = lane >> 4;
  const float* b1e = b1 + e * DFF;
#pragma unroll
  for (int mi = 0; mi < 8; ++mi) {
#pragma unroll
    for (int r = 0; r < 4; ++r) {
      int m = m0 + wm + mi * 16 + lg * 4 + r;
      if (m >= cnt) continue;
      long hrow = (long)(bas + m) * DFF;
#pragma unroll
      for (int ni = 0; ni < 4; ++ni) {
        int f = n0 + wn + ni * 16 + lr;
        float v = acc[mi][ni][r] + b1e[f];
        h[hrow + f] = f2bf(fmaxf(v, 0.f));
      }
    }
  }
}

// ---------------- GEMM2: y[slot] = gate * (h[slot] @ W2 + b2) ----------------
__global__ __launch_bounds__(512) void gemm2_kernel(
    const ushort* __restrict__ h, const ushort* __restrict__ w2t,
    const float* __restrict__ b2, const int* __restrict__ meta,
    const float* __restrict__ gate, ushort* __restrict__ y) {
  int nwg = 32 * (DMODEL / 256) * NEXP;
  int flat = blockIdx.x;
  int wgid = (flat % 8) * (nwg / 8) + flat / 8;
  int m0 = (wgid % 32) * 256;
  int rest = wgid / 32;
  int n0 = (rest % (DMODEL / 256)) * 256;
  int e = rest / (DMODEL / 256);
  int cnt = meta[e];
  if (m0 >= cnt) return;
  int bas = meta[16 + e];
  __shared__ char lds[131072];
  int tid = threadIdx.x;

  const char* w2e = (const char*)(w2t + (long)e * DMODEL * DFF + (long)n0 * DFF);
  int r0 = tid >> 2;
  int ma = m0 + r0; if (ma >= cnt) ma = cnt - 1;
  int mb = m0 + r0 + 128; if (mb >= cnt) mb = cnt - 1;
  const char* aP0 = (const char*)h + (long)(bas + ma) * (DFF * 2);
  const char* aP1 = (const char*)h + (long)(bas + mb) * (DFF * 2);
  const char* bP0 = w2e + (long)r0 * (DFF * 2);
  const char* bP1 = w2e + (long)(r0 + 128) * (DFF * 2);

  floatx4 acc[8][4];
#pragma unroll
  for (int i = 0; i < 8; ++i)
#pragma unroll
    for (int j = 0; j < 4; ++j) acc[i][j] = (floatx4){0.f, 0.f, 0.f, 0.f};

  gemm_pipe(DFF / 64, aP0, aP1, bP0, bP1, lds, tid, acc);

  int lane = tid & 63, wid = tid >> 6;
  int wm = (wid >> 2) * 128, wn = (wid & 3) * 64;
  int lr = lane & 15, lg = lane >> 4;
  const float* b2e = b2 + e * DMODEL;
#pragma unroll
  for (int mi = 0; mi < 8; ++mi) {
#pragma unroll
    for (int r = 0; r < 4; ++r) {
      int m = m0 + wm + mi * 16 + lg * 4 + r;
      if (m >= cnt) continue;
      int slot = bas + m;
      float g = gate[slot];
      ushort* yr = y + (long)slot * DMODEL;
#pragma unroll
      for (int ni = 0; ni < 4; ++ni) {
        int n = n0 + wn + ni * 16 + lr;
        float v = g * (acc[mi][ni][r] + b2e[n]);
        yr[n] = f2bf(v);
      }
    }
  }
}

// ---------------- combine: out[t] = y[slot1] + y[slot2]; entropy copy ----------------
__global__ __launch_bounds__(256) void combine_kernel(
    const ushort* __restrict__ y, const int* __restrict__ slotOf,
    const float* __restrict__ entWs, float* __restrict__ out) {
  int t = blockIdx.x;
  int s1 = slotOf[2 * t], s2 = slotOf[2 * t + 1];
  int d = threadIdx.x * 4;
  ushort4v a = *(const ushort4v*)&y[(long)s1 * DMODEL + d];
  ushort4v b = *(const ushort4v*)&y[(long)s2 * DMODEL + d];
  float4 r;
  r.x = bf2f(a[0]) + bf2f(b[0]);
  r.y = bf2f(a[1]) + bf2f(b[1]);
  r.z = bf2f(a[2]) + bf2f(b[2]);
  r.w = bf2f(a[3]) + bf2f(b[3]);
  *(float4*)&out[(long)t * DMODEL + d] = r;
  if (t == 0 && threadIdx.x == 0) out[(long)T_TOK * DMODEL] = *entWs;
}

extern "C" void kernel_launch(void* const* d_in, const int* in_sizes, int n_in,
                              void* d_out, int out_size, void* d_ws, size_t ws_size,
                              hipStream_t stream) {
  const float* x  = (const float*)d_in[0];
  const float* Wg = (const float*)d_in[1];
  const float* bg = (const float*)d_in[2];
  const float* W1 = (const float*)d_in[3];
  const float* b1 = (const float*)d_in[4];
  const float* W2 = (const float*)d_in[5];
  const float* b2 = (const float*)d_in[6];
  float* out = (float*)d_out;

  char* ws = (char*)d_ws;
  int*    meta   = (int*)(ws + 0);
  float*  entWs  = (float*)(ws + 256);
  int*    te     = (int*)(ws + 1024);
  float*  tg     = (float*)(ws + 66560);
  int*    tokA   = (int*)(ws + 132096);
  float*  gate   = (float*)(ws + 197632);
  int*    slotOf = (int*)(ws + 263168);
  ushort* xb     = (ushort*)(ws + 328704);    // 16 MB
  ushort* w1t    = (ushort*)(ws + 17105920);  // 32 MB (dead after gemm1 -> reused as y)
  ushort* w2t    = (ushort*)(ws + 50660352);  // 32 MB
  ushort* h      = (ushort*)(ws + 84214784);  // 64 MB
  ushort* y      = w1t;

  init_kernel<<<1, 64, 0, stream>>>(meta, entWs);
  gating_kernel<<<T_TOK / 4, 256, 0, stream>>>(x, Wg, bg, meta, te, tg, entWs, xb);
  prefix_kernel<<<1, 1, 0, stream>>>(meta);
  scatter_kernel<<<T_TOK / 256, 256, 0, stream>>>(te, tg, meta, tokA, gate, slotOf);
  tcvt_kernel<<<dim3(DFF / 64, DMODEL / 64, NEXP), 256, 0, stream>>>(W1, w1t, DMODEL, DFF);
  tcvt_kernel<<<dim3(DMODEL / 64, DFF / 64, NEXP), 256, 0, stream>>>(W2, w2t, DFF, DMODEL);
  gemm1_kernel<<<32 * (DFF / 256) * NEXP, 512, 0, stream>>>(xb, w1t, b1, meta, tokA, h);
  gemm2_kernel<<<32 * (DMODEL / 256) * NEXP, 512, 0, stream>>>(h, w2t, b2, meta, gate, y);
  combine_kernel<<<T_TOK, 256, 0, stream>>>(y, slotOf, entWs, out);
}

// Round 6
// 349.624 us; speedup vs baseline: 3.9626x; 1.5048x over previous
//
#include <hip/hip_runtime.h>
#include <hip/hip_bf16.h>

#define T_TOK 8192
#define DMODEL 1024
#define DFF 2048
#define NEXP 8

typedef __attribute__((ext_vector_type(8))) short short8v;
typedef __attribute__((ext_vector_type(4))) float floatx4;
typedef __attribute__((ext_vector_type(4))) ushort ushort4v;

__device__ __forceinline__ ushort f2bf(float f) {
  union { float f; unsigned u; } v; v.f = f;
  unsigned u = v.u;
  unsigned r = (u + 0x7FFFu + ((u >> 16) & 1u)) >> 16;
  return (ushort)r;
}
__device__ __forceinline__ float bf2f(ushort b) {
  union { unsigned u; float f; } v; v.u = ((unsigned)b) << 16;
  return v.f;
}
__device__ __forceinline__ void gload16(const void* g, void* l) {
  __builtin_amdgcn_global_load_lds(
      (const __attribute__((address_space(1))) unsigned int*)g,
      (__attribute__((address_space(3))) unsigned int*)l, 16, 0, 0);
}
__device__ __forceinline__ short8v dsr128(unsigned off) {
  short8v r;
  asm volatile("ds_read_b128 %0, %1" : "=v"(r) : "v"(off));
  return r;
}
#define VMW(n) asm volatile("s_waitcnt vmcnt(" #n ")" ::: "memory")
#define LG0()  asm volatile("s_waitcnt lgkmcnt(0)" ::: "memory")
#define BAR()  asm volatile("s_barrier" ::: "memory")
#define SB0()  __builtin_amdgcn_sched_barrier(0)

// ---------------- init ----------------
__global__ void init_kernel(int* __restrict__ meta, float* __restrict__ entWs) {
  if (threadIdx.x < 64) meta[threadIdx.x] = 0;
  if (threadIdx.x == 0) *entWs = 0.f;
}

// ---------------- gating: 16 tokens/block, conflict-free Wg LDS, fused x->bf16 ----------------
// norm-modulation in the reference is a per-token uniform shift across experts:
// invariant for top-k indices and softmax(topv) -> skipped entirely.
// Wg LDS layout: addr(d,e) = 8d + e + (d>>2)  [monotone pad -> injective; the
// earlier (d>>2)&31 wrapped 31->0 and collided blocks q=31/q=32].
// Read bank = (33*lane + 8j + e) mod 32 -> bijective in lane mod 32 -> 2-way (free).
__global__ __launch_bounds__(256) void gating_kernel(
    const float* __restrict__ x, const float* __restrict__ Wg,
    const float* __restrict__ bg, int* __restrict__ meta,
    int* __restrict__ te, float* __restrict__ tg, float* __restrict__ entWs,
    ushort* __restrict__ xb) {
  __shared__ float wgT[8448];
  __shared__ float sbg[NEXP];
  __shared__ int cnt_s[NEXP];
  __shared__ float ent_s;
  int tid = threadIdx.x;
#pragma unroll
  for (int k = 0; k < 8; ++k) {
    int g4 = tid + 256 * k;               // float4 group index, 2048 total
    float4 v = ((const float4*)Wg)[g4];
    int q = g4 * 4;
    int f = q >> 5;                        // == d>>2 for all 4 elements (q%32<=28)
    wgT[q + f]     = v.x;
    wgT[q + 1 + f] = v.y;
    wgT[q + 2 + f] = v.z;
    wgT[q + 3 + f] = v.w;
  }
  if (tid < NEXP) { sbg[tid] = bg[tid]; cnt_s[tid] = 0; }
  if (tid == 0) ent_s = 0.f;
  __syncthreads();

  int wid = tid >> 6, lane = tid & 63;
#pragma unroll 1
  for (int it = 0; it < 4; ++it) {
    int t = blockIdx.x * 16 + wid * 4 + it;
    const float* xr = x + (long)t * DMODEL;
    ushort* xbr = xb + (long)t * DMODEL;
    float acc[NEXP];
#pragma unroll
    for (int e = 0; e < NEXP; ++e) acc[e] = 0.f;
#pragma unroll
    for (int i = 0; i < 4; ++i) {
      int dbase = i * 256 + lane * 4;
      int pad = i * 64 + lane;             // == d>>2 for d = dbase..dbase+3
      float4 xv = *(const float4*)(xr + dbase);
      ushort4v s;
      s[0] = f2bf(xv.x); s[1] = f2bf(xv.y); s[2] = f2bf(xv.z); s[3] = f2bf(xv.w);
      *(ushort4v*)(xbr + dbase) = s;
      float xj[4] = {xv.x, xv.y, xv.z, xv.w};
#pragma unroll
      for (int j = 0; j < 4; ++j) {
        int base = 8 * (dbase + j) + pad;
#pragma unroll
        for (int e = 0; e < NEXP; ++e) acc[e] += xj[j] * wgT[base + e];
      }
    }
#pragma unroll
    for (int off = 32; off; off >>= 1)
#pragma unroll
      for (int e = 0; e < NEXP; ++e) acc[e] += __shfl_xor(acc[e], off, 64);
    if (lane == 0) {
      float lg[NEXP];
#pragma unroll
      for (int e = 0; e < NEXP; ++e) lg[e] = acc[e] + sbg[e];
      int e1 = 0; float v1 = lg[0];
#pragma unroll
      for (int e = 1; e < NEXP; ++e) if (lg[e] > v1) { v1 = lg[e]; e1 = e; }
      int e2 = -1; float v2 = -1e30f;
#pragma unroll
      for (int e = 0; e < NEXP; ++e) if (e != e1 && lg[e] > v2) { v2 = lg[e]; e2 = e; }
      float p2 = expf(v2 - v1);
      float s = 1.f + p2;
      float g1 = 1.f / s, g2 = p2 / s;
      float ent = -(g1 * logf(fmaxf(g1, 1e-8f)) + g2 * logf(fmaxf(g2, 1e-8f)));
      atomicAdd(&cnt_s[e1], 1);
      atomicAdd(&cnt_s[e2], 1);
      atomicAdd(&ent_s, ent);
      te[2 * t] = e1; te[2 * t + 1] = e2;
      tg[2 * t] = g1; tg[2 * t + 1] = g2;
    }
  }
  __syncthreads();
  if (tid < NEXP && cnt_s[tid]) atomicAdd(&meta[tid], cnt_s[tid]);
  if (tid == 0) atomicAdd(entWs, ent_s * (1.f / T_TOK));
}

// meta layout (ints): counts @0..7, base @16..23, cursor @32..39
__global__ void prefix_kernel(int* __restrict__ meta) {
  if (threadIdx.x == 0) {
    int s = 0;
    for (int e = 0; e < NEXP; ++e) { meta[16 + e] = s; s += meta[e]; meta[32 + e] = 0; }
  }
}

__global__ void scatter_kernel(const int* __restrict__ te, const float* __restrict__ tg,
                               int* __restrict__ meta, int* __restrict__ tok,
                               float* __restrict__ gate, int* __restrict__ slotOf) {
  int t = blockIdx.x * blockDim.x + threadIdx.x;
  if (t >= T_TOK) return;
  for (int k = 0; k < 2; ++k) {
    int e = te[2 * t + k];
    int pos = atomicAdd(&meta[32 + e], 1);
    int slot = meta[16 + e] + pos;
    tok[slot] = t;
    gate[slot] = tg[2 * t + k];
    slotOf[2 * t + k] = slot;
  }
}

// ---------------- transpose + convert weights: src[e][R][C] f32 -> dst[e][C][R] bf16 ----------------
__global__ __launch_bounds__(256) void tcvt_kernel(const float* __restrict__ src,
                                                   ushort* __restrict__ dst,
                                                   int R, int C) {
  __shared__ ushort tile[64][72];
  int tid = threadIdx.x;
  long eoff = (long)blockIdx.z * R * C;
  int r0 = blockIdx.y * 64, c0 = blockIdx.x * 64;
  int lr = tid >> 4, lc = (tid & 15) * 4;
#pragma unroll
  for (int p = 0; p < 4; ++p) {
    int r = lr + p * 16;
    float4 v = *(const float4*)&src[eoff + (long)(r0 + r) * C + (c0 + lc)];
    tile[r][lc + 0] = f2bf(v.x); tile[r][lc + 1] = f2bf(v.y);
    tile[r][lc + 2] = f2bf(v.z); tile[r][lc + 3] = f2bf(v.w);
  }
  __syncthreads();
  int sr = tid >> 3, sc = (tid & 7) * 8;
#pragma unroll
  for (int p = 0; p < 2; ++p) {
    int c = sr + p * 32;
    short8v v;
#pragma unroll
    for (int j = 0; j < 8; ++j) v[j] = (short)tile[sc + j][c];
    *(short8v*)&dst[eoff + (long)(c0 + c) * R + (r0 + sc)] = v;
  }
}

// ================= 8-phase pipelined grouped GEMM core =================
// 256x256 tile, BK=64 split into two ks-halves; LDS [buf][ks][256][32] bf16,
// XOR-swizzle ((row>>1)&3)<<4 within the 64B half (2-way conflicts = free).
// Counted vmcnt: 8 in steady state (4 half-tiles in flight), 4/0 in tail.
__device__ __forceinline__ void gemm_pipe(
    int NT, const char* aP0, const char* aP1, const char* bP0, const char* bP1,
    char* lds, int tid, floatx4 (&acc)[8][4]) {
  const unsigned ldsU = (unsigned)(unsigned long)lds;
  int lane = tid & 63, wid = tid >> 6;
  int wm = (wid >> 2) * 128, wn = (wid & 3) * 64;
  int lr = lane & 15, lg = lane >> 4;
  unsigned offA[8], offB[4];
#pragma unroll
  for (int mi = 0; mi < 8; ++mi) {
    int row = wm + mi * 16 + lr;
    offA[mi] = row * 64 + ((lg * 16) ^ (((row >> 1) & 3) << 4));
  }
#pragma unroll
  for (int ni = 0; ni < 4; ++ni) {
    int row = wn + ni * 16 + lr;
    offB[ni] = row * 64 + ((lg * 16) ^ (((row >> 1) & 3) << 4));
  }
  int r0 = tid >> 2, r1 = r0 + 128;
  unsigned scol0 = ((tid & 3) * 16) ^ (((r0 >> 1) & 3) << 4);
  unsigned scol1 = ((tid & 3) * 16) ^ (((r1 >> 1) & 3) << 4);

  auto STG_A = [&](int buf, int ks, int t) {
    int koff = t * 128 + ks * 64;
    int reg = (buf * 2 + ks) * 16384;
    gload16(aP0 + koff + scol0, lds + reg + tid * 16);
    gload16(aP1 + koff + scol1, lds + reg + 8192 + tid * 16);
  };
  auto STG_B = [&](int buf, int ks, int t) {
    int koff = t * 128 + ks * 64;
    int reg = 65536 + (buf * 2 + ks) * 16384;
    gload16(bP0 + koff + scol0, lds + reg + tid * 16);
    gload16(bP1 + koff + scol1, lds + reg + 8192 + tid * 16);
  };
  auto RDA = [&](int buf, int ks, int mi) {
    return dsr128(ldsU + (unsigned)((buf * 2 + ks) * 16384) + offA[mi]);
  };
  auto RDB = [&](int buf, int ks, int ni) {
    return dsr128(ldsU + (unsigned)(65536 + (buf * 2 + ks) * 16384) + offB[ni]);
  };
  auto MM = [&](int mh, short8v* af, short8v* bf) {
#pragma unroll
    for (int mi = 0; mi < 4; ++mi)
#pragma unroll
      for (int ni = 0; ni < 4; ++ni)
        acc[mh * 4 + mi][ni] =
            __builtin_amdgcn_mfma_f32_16x16x32_bf16(af[mi], bf[ni], acc[mh * 4 + mi][ni], 0, 0, 0);
  };

  // prologue: t0 all 4 half-tiles, t1 ks0 halves (12 loads); wait first 4.
  STG_A(0, 0, 0); STG_B(0, 0, 0);
  STG_A(0, 1, 0); STG_B(0, 1, 0);
  STG_A(1, 0, 1); STG_B(1, 0, 1);
  VMW(8); BAR();

  short8v af[4], bf0[4], bf1[4];
  for (int t = 0; t + 2 < NT; ++t) {
    int buf = t & 1, nb = buf ^ 1;
    // ph0: (ks0, mh0) ; stage (t+1).A.ks1
#pragma unroll
    for (int ni = 0; ni < 4; ++ni) bf0[ni] = RDB(buf, 0, ni);
#pragma unroll
    for (int i = 0; i < 4; ++i) af[i] = RDA(buf, 0, i);
    STG_A(nb, 1, t + 1);
    BAR(); LG0(); SB0();
    __builtin_amdgcn_s_setprio(1); MM(0, af, bf0); __builtin_amdgcn_s_setprio(0);
    SB0(); BAR();
    // ph1: (ks0, mh1) ; stage (t+1).B.ks1 ; vmcnt(8)
#pragma unroll
    for (int i = 0; i < 4; ++i) af[i] = RDA(buf, 0, 4 + i);
    STG_B(nb, 1, t + 1);
    VMW(8);
    BAR(); LG0(); SB0();
    __builtin_amdgcn_s_setprio(1); MM(1, af, bf0); __builtin_amdgcn_s_setprio(0);
    SB0(); BAR();
    // ph2: (ks1, mh0) ; stage (t+2).A.ks0
#pragma unroll
    for (int ni = 0; ni < 4; ++ni) bf1[ni] = RDB(buf, 1, ni);
#pragma unroll
    for (int i = 0; i < 4; ++i) af[i] = RDA(buf, 1, i);
    STG_A(buf, 0, t + 2);
    BAR(); LG0(); SB0();
    __builtin_amdgcn_s_setprio(1); MM(0, af, bf1); __builtin_amdgcn_s_setprio(0);
    SB0(); BAR();
    // ph3: (ks1, mh1) ; stage (t+2).B.ks0 ; vmcnt(8)
#pragma unroll
    for (int i = 0; i < 4; ++i) af[i] = RDA(buf, 1, 4 + i);
    STG_B(buf, 0, t + 2);
    VMW(8);
    BAR(); LG0(); SB0();
    __builtin_amdgcn_s_setprio(1); MM(1, af, bf1); __builtin_amdgcn_s_setprio(0);
    SB0(); BAR();
  }
  { // tile NT-2: stage only (NT-1).ks1 halves; waits 8 then 4
    int t = NT - 2, buf = t & 1, nb = buf ^ 1;
#pragma unroll
    for (int ni = 0; ni < 4; ++ni) bf0[ni] = RDB(buf, 0, ni);
#pragma unroll
    for (int i = 0; i < 4; ++i) af[i] = RDA(buf, 0, i);
    STG_A(nb, 1, t + 1);
    BAR(); LG0(); SB0();
    __builtin_amdgcn_s_setprio(1); MM(0, af, bf0); __builtin_amdgcn_s_setprio(0);
    SB0(); BAR();
#pragma unroll
    for (int i = 0; i < 4; ++i) af[i] = RDA(buf, 0, 4 + i);
    STG_B(nb, 1, t + 1);
    VMW(8);
    BAR(); LG0(); SB0();
    __builtin_amdgcn_s_setprio(1); MM(1, af, bf0); __builtin_amdgcn_s_setprio(0);
    SB0(); BAR();
#pragma unroll
    for (int ni = 0; ni < 4; ++ni) bf1[ni] = RDB(buf, 1, ni);
#pragma unroll
    for (int i = 0; i < 4; ++i) af[i] = RDA(buf, 1, i);
    BAR(); LG0(); SB0();
    __builtin_amdgcn_s_setprio(1); MM(0, af, bf1); __builtin_amdgcn_s_setprio(0);
    SB0(); BAR();
#pragma unroll
    for (int i = 0; i < 4; ++i) af[i] = RDA(buf, 1, 4 + i);
    VMW(4);
    BAR(); LG0(); SB0();
    __builtin_amdgcn_s_setprio(1); MM(1, af, bf1); __builtin_amdgcn_s_setprio(0);
    SB0(); BAR();
  }
  { // tile NT-1: no stages; vmcnt(0) before ks1 reads
    int t = NT - 1, buf = t & 1;
#pragma unroll
    for (int ni = 0; ni < 4; ++ni) bf0[ni] = RDB(buf, 0, ni);
#pragma unroll
    for (int i = 0; i < 4; ++i) af[i] = RDA(buf, 0, i);
    BAR(); LG0(); SB0();
    __builtin_amdgcn_s_setprio(1); MM(0, af, bf0); __builtin_amdgcn_s_setprio(0);
    SB0(); BAR();
#pragma unroll
    for (int i = 0; i < 4; ++i) af[i] = RDA(buf, 0, 4 + i);
    VMW(0);
    BAR(); LG0(); SB0();
    __builtin_amdgcn_s_setprio(1); MM(1, af, bf0); __builtin_amdgcn_s_setprio(0);
    SB0(); BAR();
#pragma unroll
    for (int ni = 0; ni < 4; ++ni) bf1[ni] = RDB(buf, 1, ni);
#pragma unroll
    for (int i = 0; i < 4; ++i) af[i] = RDA(buf, 1, i);
    BAR(); LG0(); SB0();
    __builtin_amdgcn_s_setprio(1); MM(0, af, bf1); __builtin_amdgcn_s_setprio(0);
    SB0(); BAR();
#pragma unroll
    for (int i = 0; i < 4; ++i) af[i] = RDA(buf, 1, 4 + i);
    BAR(); LG0(); SB0();
    __builtin_amdgcn_s_setprio(1); MM(1, af, bf1); __builtin_amdgcn_s_setprio(0);
    SB0(); BAR();
  }
}

// ---------------- GEMM1: h = relu(x[tok] @ W1 + b1) ----------------
__global__ __launch_bounds__(512) void gemm1_kernel(
    const ushort* __restrict__ xb, const ushort* __restrict__ w1t,
    const float* __restrict__ b1, const int* __restrict__ meta,
    const int* __restrict__ tok, ushort* __restrict__ h) {
  // bijective XCD swizzle (m204); wgid order: m fastest, then n, then e
  int nwg = 32 * (DFF / 256) * NEXP;
  int flat = blockIdx.x;
  int wgid = (flat % 8) * (nwg / 8) + flat / 8;
  int m0 = (wgid % 32) * 256;
  int rest = wgid / 32;
  int n0 = (rest % (DFF / 256)) * 256;
  int e = rest / (DFF / 256);
  int cnt = meta[e];
  if (m0 >= cnt) return;
  int bas = meta[16 + e];
  __shared__ char lds[131072];
  int tid = threadIdx.x;

  const char* w1e = (const char*)(w1t + (long)e * DFF * DMODEL + (long)n0 * DMODEL);
  int r0 = tid >> 2;
  int ma = m0 + r0; if (ma >= cnt) ma = cnt - 1;
  int mb = m0 + r0 + 128; if (mb >= cnt) mb = cnt - 1;
  const char* aP0 = (const char*)xb + (long)tok[bas + ma] * (DMODEL * 2);
  const char* aP1 = (const char*)xb + (long)tok[bas + mb] * (DMODEL * 2);
  const char* bP0 = w1e + (long)r0 * (DMODEL * 2);
  const char* bP1 = w1e + (long)(r0 + 128) * (DMODEL * 2);

  floatx4 acc[8][4];
#pragma unroll
  for (int i = 0; i < 8; ++i)
#pragma unroll
    for (int j = 0; j < 4; ++j) acc[i][j] = (floatx4){0.f, 0.f, 0.f, 0.f};

  gemm_pipe(DMODEL / 64, aP0, aP1, bP0, bP1, lds, tid, acc);

  int lane = tid & 63, wid = tid >> 6;
  int wm = (wid >> 2) * 128, wn = (wid & 3) * 64;
  int lr = lane & 15, lg = lane >> 4;
  const float* b1e = b1 + e * DFF;
#pragma unroll
  for (int mi = 0; mi < 8; ++mi) {
#pragma unroll
    for (int r = 0; r < 4; ++r) {
      int m = m0 + wm + mi * 16 + lg * 4 + r;
      if (m >= cnt) continue;
      long hrow = (long)(bas + m) * DFF;
#pragma unroll
      for (int ni = 0; ni < 4; ++ni) {
        int f = n0 + wn + ni * 16 + lr;
        float v = acc[mi][ni][r] + b1e[f];
        h[hrow + f] = f2bf(fmaxf(v, 0.f));
      }
    }
  }
}

// ---------------- GEMM2: y[slot] = gate * (h[slot] @ W2 + b2) ----------------
__global__ __launch_bounds__(512) void gemm2_kernel(
    const ushort* __restrict__ h, const ushort* __restrict__ w2t,
    const float* __restrict__ b2, const int* __restrict__ meta,
    const float* __restrict__ gate, ushort* __restrict__ y) {
  int nwg = 32 * (DMODEL / 256) * NEXP;
  int flat = blockIdx.x;
  int wgid = (flat % 8) * (nwg / 8) + flat / 8;
  int m0 = (wgid % 32) * 256;
  int rest = wgid / 32;
  int n0 = (rest % (DMODEL / 256)) * 256;
  int e = rest / (DMODEL / 256);
  int cnt = meta[e];
  if (m0 >= cnt) return;
  int bas = meta[16 + e];
  __shared__ char lds[131072];
  int tid = threadIdx.x;

  const char* w2e = (const char*)(w2t + (long)e * DMODEL * DFF + (long)n0 * DFF);
  int r0 = tid >> 2;
  int ma = m0 + r0; if (ma >= cnt) ma = cnt - 1;
  int mb = m0 + r0 + 128; if (mb >= cnt) mb = cnt - 1;
  const char* aP0 = (const char*)h + (long)(bas + ma) * (DFF * 2);
  const char* aP1 = (const char*)h + (long)(bas + mb) * (DFF * 2);
  const char* bP0 = w2e + (long)r0 * (DFF * 2);
  const char* bP1 = w2e + (long)(r0 + 128) * (DFF * 2);

  floatx4 acc[8][4];
#pragma unroll
  for (int i = 0; i < 8; ++i)
#pragma unroll
    for (int j = 0; j < 4; ++j) acc[i][j] = (floatx4){0.f, 0.f, 0.f, 0.f};

  gemm_pipe(DFF / 64, aP0, aP1, bP0, bP1, lds, tid, acc);

  int lane = tid & 63, wid = tid >> 6;
  int wm = (wid >> 2) * 128, wn = (wid & 3) * 64;
  int lr = lane & 15, lg = lane >> 4;
  const float* b2e = b2 + e * DMODEL;
#pragma unroll
  for (int mi = 0; mi < 8; ++mi) {
#pragma unroll
    for (int r = 0; r < 4; ++r) {
      int m = m0 + wm + mi * 16 + lg * 4 + r;
      if (m >= cnt) continue;
      int slot = bas + m;
      float g = gate[slot];
      ushort* yr = y + (long)slot * DMODEL;
#pragma unroll
      for (int ni = 0; ni < 4; ++ni) {
        int n = n0 + wn + ni * 16 + lr;
        float v = g * (acc[mi][ni][r] + b2e[n]);
        yr[n] = f2bf(v);
      }
    }
  }
}

// ---------------- combine: out[t] = y[slot1] + y[slot2]; entropy copy ----------------
__global__ __launch_bounds__(256) void combine_kernel(
    const ushort* __restrict__ y, const int* __restrict__ slotOf,
    const float* __restrict__ entWs, float* __restrict__ out) {
  int t = blockIdx.x;
  int s1 = slotOf[2 * t], s2 = slotOf[2 * t + 1];
  int d = threadIdx.x * 4;
  ushort4v a = *(const ushort4v*)&y[(long)s1 * DMODEL + d];
  ushort4v b = *(const ushort4v*)&y[(long)s2 * DMODEL + d];
  float4 r;
  r.x = bf2f(a[0]) + bf2f(b[0]);
  r.y = bf2f(a[1]) + bf2f(b[1]);
  r.z = bf2f(a[2]) + bf2f(b[2]);
  r.w = bf2f(a[3]) + bf2f(b[3]);
  *(float4*)&out[(long)t * DMODEL + d] = r;
  if (t == 0 && threadIdx.x == 0) out[(long)T_TOK * DMODEL] = *entWs;
}

extern "C" void kernel_launch(void* const* d_in, const int* in_sizes, int n_in,
                              void* d_out, int out_size, void* d_ws, size_t ws_size,
                              hipStream_t stream) {
  const float* x  = (const float*)d_in[0];
  const float* Wg = (const float*)d_in[1];
  const float* bg = (const float*)d_in[2];
  const float* W1 = (const float*)d_in[3];
  const float* b1 = (const float*)d_in[4];
  const float* W2 = (const float*)d_in[5];
  const float* b2 = (const float*)d_in[6];
  float* out = (float*)d_out;

  char* ws = (char*)d_ws;
  int*    meta   = (int*)(ws + 0);
  float*  entWs  = (float*)(ws + 256);
  int*    te     = (int*)(ws + 1024);
  float*  tg     = (float*)(ws + 66560);
  int*    tokA   = (int*)(ws + 132096);
  float*  gate   = (float*)(ws + 197632);
  int*    slotOf = (int*)(ws + 263168);
  ushort* xb     = (ushort*)(ws + 328704);    // 16 MB
  ushort* w1t    = (ushort*)(ws + 17105920);  // 32 MB (dead after gemm1 -> reused as y)
  ushort* w2t    = (ushort*)(ws + 50660352);  // 32 MB
  ushort* h      = (ushort*)(ws + 84214784);  // 64 MB
  ushort* y      = w1t;

  init_kernel<<<1, 64, 0, stream>>>(meta, entWs);
  gating_kernel<<<T_TOK / 16, 256, 0, stream>>>(x, Wg, bg, meta, te, tg, entWs, xb);
  prefix_kernel<<<1, 1, 0, stream>>>(meta);
  scatter_kernel<<<T_TOK / 256, 256, 0, stream>>>(te, tg, meta, tokA, gate, slotOf);
  tcvt_kernel<<<dim3(DFF / 64, DMODEL / 64, NEXP), 256, 0, stream>>>(W1, w1t, DMODEL, DFF);
  tcvt_kernel<<<dim3(DMODEL / 64, DFF / 64, NEXP), 256, 0, stream>>>(W2, w2t, DFF, DMODEL);
  gemm1_kernel<<<32 * (DFF / 256) * NEXP, 512, 0, stream>>>(xb, w1t, b1, meta, tokA, h);
  gemm2_kernel<<<32 * (DMODEL / 256) * NEXP, 512, 0, stream>>>(h, w2t, b2, meta, gate, y);
  combine_kernel<<<T_TOK, 256, 0, stream>>>(y, slotOf, entWs, out);
}

// Round 7
// 336.723 us; speedup vs baseline: 4.1144x; 1.0383x over previous
//
#include <hip/hip_runtime.h>
#include <hip/hip_bf16.h>

#define T_TOK 8192
#define DMODEL 1024
#define DFF 2048
#define NEXP 8

typedef __attribute__((ext_vector_type(8))) short short8v;
typedef __attribute__((ext_vector_type(4))) float floatx4;
typedef __attribute__((ext_vector_type(4))) ushort ushort4v;

__device__ __forceinline__ ushort f2bf(float f) {
  union { float f; unsigned u; } v; v.f = f;
  unsigned u = v.u;
  unsigned r = (u + 0x7FFFu + ((u >> 16) & 1u)) >> 16;
  return (ushort)r;
}
__device__ __forceinline__ float bf2f(ushort b) {
  union { unsigned u; float f; } v; v.u = ((unsigned)b) << 16;
  return v.f;
}
__device__ __forceinline__ void gload16(const void* g, void* l) {
  __builtin_amdgcn_global_load_lds(
      (const __attribute__((address_space(1))) unsigned int*)g,
      (__attribute__((address_space(3))) unsigned int*)l, 16, 0, 0);
}
__device__ __forceinline__ short8v dsr128(unsigned off) {
  short8v r;
  asm volatile("ds_read_b128 %0, %1" : "=v"(r) : "v"(off));
  return r;
}
#define VMW(n) asm volatile("s_waitcnt vmcnt(" #n ")" ::: "memory")
#define LG0()  asm volatile("s_waitcnt lgkmcnt(0)" ::: "memory")
#define BAR()  asm volatile("s_barrier" ::: "memory")
#define SB0()  __builtin_amdgcn_sched_barrier(0)

// ---------------- init ----------------
__global__ void init_kernel(int* __restrict__ meta, float* __restrict__ entWs) {
  if (threadIdx.x < 64) meta[threadIdx.x] = 0;
  if (threadIdx.x == 0) *entWs = 0.f;
}

// ---------------- gating: 16 tokens/block, conflict-free Wg LDS, fused x->bf16 ----------------
// norm-modulation in the reference is a per-token uniform shift across experts:
// invariant for top-k indices and softmax(topv) -> skipped entirely.
// Wg LDS layout: addr(d,e) = 8d + e + (d>>2) (monotone pad -> injective).
__global__ __launch_bounds__(256) void gating_kernel(
    const float* __restrict__ x, const float* __restrict__ Wg,
    const float* __restrict__ bg, int* __restrict__ meta,
    int* __restrict__ te, float* __restrict__ tg, float* __restrict__ entWs,
    ushort* __restrict__ xb) {
  __shared__ float wgT[8448];
  __shared__ float sbg[NEXP];
  __shared__ int cnt_s[NEXP];
  __shared__ float ent_s;
  int tid = threadIdx.x;
#pragma unroll
  for (int k = 0; k < 8; ++k) {
    int g4 = tid + 256 * k;
    float4 v = ((const float4*)Wg)[g4];
    int q = g4 * 4;
    int f = q >> 5;
    wgT[q + f]     = v.x;
    wgT[q + 1 + f] = v.y;
    wgT[q + 2 + f] = v.z;
    wgT[q + 3 + f] = v.w;
  }
  if (tid < NEXP) { sbg[tid] = bg[tid]; cnt_s[tid] = 0; }
  if (tid == 0) ent_s = 0.f;
  __syncthreads();

  int wid = tid >> 6, lane = tid & 63;
#pragma unroll 1
  for (int it = 0; it < 4; ++it) {
    int t = blockIdx.x * 16 + wid * 4 + it;
    const float* xr = x + (long)t * DMODEL;
    ushort* xbr = xb + (long)t * DMODEL;
    float acc[NEXP];
#pragma unroll
    for (int e = 0; e < NEXP; ++e) acc[e] = 0.f;
#pragma unroll
    for (int i = 0; i < 4; ++i) {
      int dbase = i * 256 + lane * 4;
      int pad = i * 64 + lane;
      float4 xv = *(const float4*)(xr + dbase);
      ushort4v s;
      s[0] = f2bf(xv.x); s[1] = f2bf(xv.y); s[2] = f2bf(xv.z); s[3] = f2bf(xv.w);
      *(ushort4v*)(xbr + dbase) = s;
      float xj[4] = {xv.x, xv.y, xv.z, xv.w};
#pragma unroll
      for (int j = 0; j < 4; ++j) {
        int base = 8 * (dbase + j) + pad;
#pragma unroll
        for (int e = 0; e < NEXP; ++e) acc[e] += xj[j] * wgT[base + e];
      }
    }
#pragma unroll
    for (int off = 32; off; off >>= 1)
#pragma unroll
      for (int e = 0; e < NEXP; ++e) acc[e] += __shfl_xor(acc[e], off, 64);
    if (lane == 0) {
      float lg[NEXP];
#pragma unroll
      for (int e = 0; e < NEXP; ++e) lg[e] = acc[e] + sbg[e];
      int e1 = 0; float v1 = lg[0];
#pragma unroll
      for (int e = 1; e < NEXP; ++e) if (lg[e] > v1) { v1 = lg[e]; e1 = e; }
      int e2 = -1; float v2 = -1e30f;
#pragma unroll
      for (int e = 0; e < NEXP; ++e) if (e != e1 && lg[e] > v2) { v2 = lg[e]; e2 = e; }
      float p2 = expf(v2 - v1);
      float s = 1.f + p2;
      float g1 = 1.f / s, g2 = p2 / s;
      float ent = -(g1 * logf(fmaxf(g1, 1e-8f)) + g2 * logf(fmaxf(g2, 1e-8f)));
      atomicAdd(&cnt_s[e1], 1);
      atomicAdd(&cnt_s[e2], 1);
      atomicAdd(&ent_s, ent);
      te[2 * t] = e1; te[2 * t + 1] = e2;
      tg[2 * t] = g1; tg[2 * t + 1] = g2;
    }
  }
  __syncthreads();
  if (tid < NEXP && cnt_s[tid]) atomicAdd(&meta[tid], cnt_s[tid]);
  if (tid == 0) atomicAdd(entWs, ent_s * (1.f / T_TOK));
}

// meta layout (ints): counts @0..7, base @16..23, cursor @32..39
__global__ void prefix_kernel(int* __restrict__ meta) {
  if (threadIdx.x == 0) {
    int s = 0;
    for (int e = 0; e < NEXP; ++e) { meta[16 + e] = s; s += meta[e]; meta[32 + e] = 0; }
  }
}

__global__ void scatter_kernel(const int* __restrict__ te, const float* __restrict__ tg,
                               int* __restrict__ meta, int* __restrict__ tok,
                               float* __restrict__ gate, int* __restrict__ slotOf) {
  int t = blockIdx.x * blockDim.x + threadIdx.x;
  if (t >= T_TOK) return;
  for (int k = 0; k < 2; ++k) {
    int e = te[2 * t + k];
    int pos = atomicAdd(&meta[32 + e], 1);
    int slot = meta[16 + e] + pos;
    tok[slot] = t;
    gate[slot] = tg[2 * t + k];
    slotOf[2 * t + k] = slot;
  }
}

// ---------------- transpose + convert weights: src[e][R][C] f32 -> dst[e][C][R] bf16 ----------------
__global__ __launch_bounds__(256) void tcvt_kernel(const float* __restrict__ src,
                                                   ushort* __restrict__ dst,
                                                   int R, int C) {
  __shared__ ushort tile[64][72];
  int tid = threadIdx.x;
  long eoff = (long)blockIdx.z * R * C;
  int r0 = blockIdx.y * 64, c0 = blockIdx.x * 64;
  int lr = tid >> 4, lc = (tid & 15) * 4;
#pragma unroll
  for (int p = 0; p < 4; ++p) {
    int r = lr + p * 16;
    float4 v = *(const float4*)&src[eoff + (long)(r0 + r) * C + (c0 + lc)];
    tile[r][lc + 0] = f2bf(v.x); tile[r][lc + 1] = f2bf(v.y);
    tile[r][lc + 2] = f2bf(v.z); tile[r][lc + 3] = f2bf(v.w);
  }
  __syncthreads();
  int sr = tid >> 3, sc = (tid & 7) * 8;
#pragma unroll
  for (int p = 0; p < 2; ++p) {
    int c = sr + p * 32;
    short8v v;
#pragma unroll
    for (int j = 0; j < 8; ++j) v[j] = (short)tile[sc + j][c];
    *(short8v*)&dst[eoff + (long)(c0 + c) * R + (r0 + sc)] = v;
  }
}

// ================= pipelined grouped GEMM core (4 waves / 256 threads) =================
// Block tile 128(M)x256(N), BK=32; wave tile 128x64 (1Mx4N), acc[8][4].
// LDS: A [3][128][32] bf16 = 24 KB @0, B [3][256][32] = 48 KB @24576 -> 72 KB
// -> 2 blocks/CU co-resident (LDS 144<=160 KB, ~206 regs <= 256 -> 8 waves/CU).
// XOR-swizzle ((row>>1)&3)<<4 within the 64B row (conflict-free, proven in r6).
// Schedule: stage tile t+2 (A in ph0: 2 gloads, B in ph1: 4 gloads), VMW(6)
// in ph1 = exactly one tile's loads in flight; 2 phases x 16 MFMA per K-tile.
__device__ __forceinline__ void gemm_pipe(
    int NT, const char* aP0, const char* aP1,
    const char* bP0, const char* bP1, const char* bP2, const char* bP3,
    char* lds, int tid, floatx4 (&acc)[8][4]) {
  const unsigned ldsU = (unsigned)(unsigned long)lds;
  int lane = tid & 63, wid = tid >> 6;
  int lr = lane & 15, lg = lane >> 4;
  unsigned offA[8], offB[4];
#pragma unroll
  for (int mi = 0; mi < 8; ++mi) {
    int row = mi * 16 + lr;
    offA[mi] = row * 64 + ((lg * 16) ^ (((row >> 1) & 3) << 4));
  }
#pragma unroll
  for (int ni = 0; ni < 4; ++ni) {
    int row = wid * 64 + ni * 16 + lr;
    offB[ni] = row * 64 + ((lg * 16) ^ (((row >> 1) & 3) << 4));
  }

  auto STG_A = [&](int b, int t) {
    int koff = t * 64;
    char* d = lds + b * 8192;
    gload16(aP0 + koff, d + tid * 16);
    gload16(aP1 + koff, d + 4096 + tid * 16);
  };
  auto STG_B = [&](int b, int t) {
    int koff = t * 64;
    char* d = lds + 24576 + b * 16384;
    gload16(bP0 + koff, d + tid * 16);
    gload16(bP1 + koff, d + 4096 + tid * 16);
    gload16(bP2 + koff, d + 8192 + tid * 16);
    gload16(bP3 + koff, d + 12288 + tid * 16);
  };
  auto RDA = [&](int b, int mi) {
    return dsr128(ldsU + (unsigned)(b * 8192) + offA[mi]);
  };
  auto RDB = [&](int b, int ni) {
    return dsr128(ldsU + (unsigned)(24576 + b * 16384) + offB[ni]);
  };
  auto MM = [&](int mh, short8v* af, short8v* bf) {
#pragma unroll
    for (int mi = 0; mi < 4; ++mi)
#pragma unroll
      for (int ni = 0; ni < 4; ++ni)
        acc[mh * 4 + mi][ni] =
            __builtin_amdgcn_mfma_f32_16x16x32_bf16(af[mi], bf[ni], acc[mh * 4 + mi][ni], 0, 0, 0);
  };

  // prologue: stage tiles 0 and 1 (12 loads); wait for tile 0's 6.
  STG_A(0, 0); STG_B(0, 0);
  STG_A(1, 1); STG_B(1, 1);
  VMW(6); BAR();

  short8v af[4], bf[4];
  int b = 0;
  for (int t = 0; t + 2 < NT; ++t) {
    int bs = (b == 0) ? 2 : b - 1;  // (b+2)%3 — buffer last read at tile t-1
    // ph0: read B(4) + A mi0-3(4); stage (t+2).A
#pragma unroll
    for (int ni = 0; ni < 4; ++ni) bf[ni] = RDB(b, ni);
#pragma unroll
    for (int i = 0; i < 4; ++i) af[i] = RDA(b, i);
    STG_A(bs, t + 2);
    BAR(); LG0(); SB0();
    __builtin_amdgcn_s_setprio(1); MM(0, af, bf); __builtin_amdgcn_s_setprio(0);
    SB0(); BAR();
    // ph1: read A mi4-7(4); stage (t+2).B; VMW(6) -> t+1's loads complete
#pragma unroll
    for (int i = 0; i < 4; ++i) af[i] = RDA(b, 4 + i);
    STG_B(bs, t + 2);
    VMW(6);
    BAR(); LG0(); SB0();
    __builtin_amdgcn_s_setprio(1); MM(1, af, bf); __builtin_amdgcn_s_setprio(0);
    SB0(); BAR();
    b = (b == 2) ? 0 : b + 1;
  }
  { // tile NT-2: no stage; VMW(0) drains tile NT-1's loads (issued at NT-3)
#pragma unroll
    for (int ni = 0; ni < 4; ++ni) bf[ni] = RDB(b, ni);
#pragma unroll
    for (int i = 0; i < 4; ++i) af[i] = RDA(b, i);
    BAR(); LG0(); SB0();
    __builtin_amdgcn_s_setprio(1); MM(0, af, bf); __builtin_amdgcn_s_setprio(0);
    SB0(); BAR();
#pragma unroll
    for (int i = 0; i < 4; ++i) af[i] = RDA(b, 4 + i);
    VMW(0);
    BAR(); LG0(); SB0();
    __builtin_amdgcn_s_setprio(1); MM(1, af, bf); __builtin_amdgcn_s_setprio(0);
    SB0(); BAR();
    b = (b == 2) ? 0 : b + 1;
  }
  { // tile NT-1: no stage, no waits beyond lgkmcnt
#pragma unroll
    for (int ni = 0; ni < 4; ++ni) bf[ni] = RDB(b, ni);
#pragma unroll
    for (int i = 0; i < 4; ++i) af[i] = RDA(b, i);
    BAR(); LG0(); SB0();
    __builtin_amdgcn_s_setprio(1); MM(0, af, bf); __builtin_amdgcn_s_setprio(0);
    SB0(); BAR();
#pragma unroll
    for (int i = 0; i < 4; ++i) af[i] = RDA(b, 4 + i);
    LG0(); SB0();
    __builtin_amdgcn_s_setprio(1); MM(1, af, bf); __builtin_amdgcn_s_setprio(0);
  }
}

// ---------------- GEMM1: h = relu(x[tok] @ W1 + b1) ----------------
__global__ __launch_bounds__(256, 2) void gemm1_kernel(
    const ushort* __restrict__ xb, const ushort* __restrict__ w1t,
    const float* __restrict__ b1, const int* __restrict__ meta,
    const int* __restrict__ tok, ushort* __restrict__ h) {
  const int NWG = 64 * 8 * NEXP;  // mtiles(128) x ntiles(256) x experts
  int flat = blockIdx.x;
  int wgid = (flat % 8) * (NWG / 8) + flat / 8;  // bijective XCD swizzle
  int m0 = (wgid & 63) * 128;
  int rest = wgid >> 6;
  int n0 = (rest & 7) * 256;
  int e = rest >> 3;
  int cnt = meta[e];
  if (m0 >= cnt) return;
  int bas = meta[16 + e];
  __shared__ char lds[73728];
  int tid = threadIdx.x;

  const char* w1e = (const char*)(w1t + (long)e * DFF * DMODEL);
  int rA = tid >> 2;
  int ch = tid & 3;
  auto sc = [&](int row) { return (unsigned)((ch * 16) ^ (((row >> 1) & 3) << 4)); };
  int ma0 = m0 + rA;        if (ma0 >= cnt) ma0 = cnt - 1;
  int ma1 = m0 + rA + 64;   if (ma1 >= cnt) ma1 = cnt - 1;
  const char* aP0 = (const char*)xb + (long)tok[bas + ma0] * (DMODEL * 2) + sc(rA);
  const char* aP1 = (const char*)xb + (long)tok[bas + ma1] * (DMODEL * 2) + sc(rA + 64);
  const char* bP0 = w1e + (long)(n0 + rA) * (DMODEL * 2) + sc(rA);
  const char* bP1 = w1e + (long)(n0 + rA + 64) * (DMODEL * 2) + sc(rA + 64);
  const char* bP2 = w1e + (long)(n0 + rA + 128) * (DMODEL * 2) + sc(rA + 128);
  const char* bP3 = w1e + (long)(n0 + rA + 192) * (DMODEL * 2) + sc(rA + 192);

  floatx4 acc[8][4];
#pragma unroll
  for (int i = 0; i < 8; ++i)
#pragma unroll
    for (int j = 0; j < 4; ++j) acc[i][j] = (floatx4){0.f, 0.f, 0.f, 0.f};

  gemm_pipe(DMODEL / 32, aP0, aP1, bP0, bP1, bP2, bP3, lds, tid, acc);

  int lane = tid & 63, wid = tid >> 6;
  int lr = lane & 15, lg = lane >> 4;
  const float* b1e = b1 + e * DFF;
#pragma unroll
  for (int mi = 0; mi < 8; ++mi) {
#pragma unroll
    for (int r = 0; r < 4; ++r) {
      int m = m0 + mi * 16 + lg * 4 + r;
      if (m >= cnt) continue;
      long hrow = (long)(bas + m) * DFF;
#pragma unroll
      for (int ni = 0; ni < 4; ++ni) {
        int f = n0 + wid * 64 + ni * 16 + lr;
        float v = acc[mi][ni][r] + b1e[f];
        h[hrow + f] = f2bf(fmaxf(v, 0.f));
      }
    }
  }
}

// ---------------- GEMM2: y[slot] = gate * (h[slot] @ W2 + b2) ----------------
__global__ __launch_bounds__(256, 2) void gemm2_kernel(
    const ushort* __restrict__ h, const ushort* __restrict__ w2t,
    const float* __restrict__ b2, const int* __restrict__ meta,
    const float* __restrict__ gate, ushort* __restrict__ y) {
  const int NWG = 64 * 4 * NEXP;
  int flat = blockIdx.x;
  int wgid = (flat % 8) * (NWG / 8) + flat / 8;
  int m0 = (wgid & 63) * 128;
  int rest = wgid >> 6;
  int n0 = (rest & 3) * 256;
  int e = rest >> 2;
  int cnt = meta[e];
  if (m0 >= cnt) return;
  int bas = meta[16 + e];
  __shared__ char lds[73728];
  int tid = threadIdx.x;

  const char* w2e = (const char*)(w2t + (long)e * DMODEL * DFF);
  int rA = tid >> 2;
  int ch = tid & 3;
  auto sc = [&](int row) { return (unsigned)((ch * 16) ^ (((row >> 1) & 3) << 4)); };
  int ma0 = m0 + rA;        if (ma0 >= cnt) ma0 = cnt - 1;
  int ma1 = m0 + rA + 64;   if (ma1 >= cnt) ma1 = cnt - 1;
  const char* aP0 = (const char*)h + (long)(bas + ma0) * (DFF * 2) + sc(rA);
  const char* aP1 = (const char*)h + (long)(bas + ma1) * (DFF * 2) + sc(rA + 64);
  const char* bP0 = w2e + (long)(n0 + rA) * (DFF * 2) + sc(rA);
  const char* bP1 = w2e + (long)(n0 + rA + 64) * (DFF * 2) + sc(rA + 64);
  const char* bP2 = w2e + (long)(n0 + rA + 128) * (DFF * 2) + sc(rA + 128);
  const char* bP3 = w2e + (long)(n0 + rA + 192) * (DFF * 2) + sc(rA + 192);

  floatx4 acc[8][4];
#pragma unroll
  for (int i = 0; i < 8; ++i)
#pragma unroll
    for (int j = 0; j < 4; ++j) acc[i][j] = (floatx4){0.f, 0.f, 0.f, 0.f};

  gemm_pipe(DFF / 32, aP0, aP1, bP0, bP1, bP2, bP3, lds, tid, acc);

  int lane = tid & 63, wid = tid >> 6;
  int lr = lane & 15, lg = lane >> 4;
  const float* b2e = b2 + e * DMODEL;
#pragma unroll
  for (int mi = 0; mi < 8; ++mi) {
#pragma unroll
    for (int r = 0; r < 4; ++r) {
      int m = m0 + mi * 16 + lg * 4 + r;
      if (m >= cnt) continue;
      int slot = bas + m;
      float g = gate[slot];
      ushort* yr = y + (long)slot * DMODEL;
#pragma unroll
      for (int ni = 0; ni < 4; ++ni) {
        int n = n0 + wid * 64 + ni * 16 + lr;
        float v = g * (acc[mi][ni][r] + b2e[n]);
        yr[n] = f2bf(v);
      }
    }
  }
}

// ---------------- combine: out[t] = y[slot1] + y[slot2]; entropy copy ----------------
__global__ __launch_bounds__(256) void combine_kernel(
    const ushort* __restrict__ y, const int* __restrict__ slotOf,
    const float* __restrict__ entWs, float* __restrict__ out) {
  int t = blockIdx.x;
  int s1 = slotOf[2 * t], s2 = slotOf[2 * t + 1];
  int d = threadIdx.x * 4;
  ushort4v a = *(const ushort4v*)&y[(long)s1 * DMODEL + d];
  ushort4v b = *(const ushort4v*)&y[(long)s2 * DMODEL + d];
  float4 r;
  r.x = bf2f(a[0]) + bf2f(b[0]);
  r.y = bf2f(a[1]) + bf2f(b[1]);
  r.z = bf2f(a[2]) + bf2f(b[2]);
  r.w = bf2f(a[3]) + bf2f(b[3]);
  *(float4*)&out[(long)t * DMODEL + d] = r;
  if (t == 0 && threadIdx.x == 0) out[(long)T_TOK * DMODEL] = *entWs;
}

extern "C" void kernel_launch(void* const* d_in, const int* in_sizes, int n_in,
                              void* d_out, int out_size, void* d_ws, size_t ws_size,
                              hipStream_t stream) {
  const float* x  = (const float*)d_in[0];
  const float* Wg = (const float*)d_in[1];
  const float* bg = (const float*)d_in[2];
  const float* W1 = (const float*)d_in[3];
  const float* b1 = (const float*)d_in[4];
  const float* W2 = (const float*)d_in[5];
  const float* b2 = (const float*)d_in[6];
  float* out = (float*)d_out;

  char* ws = (char*)d_ws;
  int*    meta   = (int*)(ws + 0);
  float*  entWs  = (float*)(ws + 256);
  int*    te     = (int*)(ws + 1024);
  float*  tg     = (float*)(ws + 66560);
  int*    tokA   = (int*)(ws + 132096);
  float*  gate   = (float*)(ws + 197632);
  int*    slotOf = (int*)(ws + 263168);
  ushort* xb     = (ushort*)(ws + 328704);    // 16 MB
  ushort* w1t    = (ushort*)(ws + 17105920);  // 32 MB (dead after gemm1 -> reused as y)
  ushort* w2t    = (ushort*)(ws + 50660352);  // 32 MB
  ushort* h      = (ushort*)(ws + 84214784);  // 64 MB
  ushort* y      = w1t;

  init_kernel<<<1, 64, 0, stream>>>(meta, entWs);
  gating_kernel<<<T_TOK / 16, 256, 0, stream>>>(x, Wg, bg, meta, te, tg, entWs, xb);
  prefix_kernel<<<1, 1, 0, stream>>>(meta);
  scatter_kernel<<<T_TOK / 256, 256, 0, stream>>>(te, tg, meta, tokA, gate, slotOf);
  tcvt_kernel<<<dim3(DFF / 64, DMODEL / 64, NEXP), 256, 0, stream>>>(W1, w1t, DMODEL, DFF);
  tcvt_kernel<<<dim3(DMODEL / 64, DFF / 64, NEXP), 256, 0, stream>>>(W2, w2t, DFF, DMODEL);
  gemm1_kernel<<<64 * 8 * NEXP, 256, 0, stream>>>(xb, w1t, b1, meta, tokA, h);
  gemm2_kernel<<<64 * 4 * NEXP, 256, 0, stream>>>(h, w2t, b2, meta, gate, y);
  combine_kernel<<<T_TOK, 256, 0, stream>>>(y, slotOf, entWs, out);
}